// Round 4
// baseline (414.396 us; speedup 1.0000x reference)
//
#include <hip/hip_runtime.h>
#include <hip/hip_bf16.h>
#include <math.h>

#define N_TOK 8192
#define HDIM  1024
#define NE    8
#define TILE  128
#define BK    32
#define NKT   (HDIM / BK)          // 32 K-steps
#define MT_MAX 64                  // 64*128 = 8192 rows capacity per expert (fully general)
#define NT_N  (HDIM / TILE)        // 8 n-tiles
#define GEMM_GRID (NE * NT_N * MT_MAX)   // 4096 blocks, ~1090 active when balanced
#define NCONV 8192                 // convert_w blocks
#define NGATE (N_TOK / 4)          // gate blocks (4 tokens each)

typedef __attribute__((ext_vector_type(8))) short bf16x8;
typedef __attribute__((ext_vector_type(4))) float f32x4;
typedef unsigned short u16;

__device__ __forceinline__ u16 f2bf(float f) {
    union { float f; unsigned u; } v; v.f = f;
    unsigned r = v.u + 0x7FFFu + ((v.u >> 16) & 1u);   // round-to-nearest-even
    return (u16)(r >> 16);
}

__device__ __forceinline__ void gld_lds16(const void* g, void* lds) {
    __builtin_amdgcn_global_load_lds(
        (const __attribute__((address_space(1))) unsigned int*)g,
        (__attribute__((address_space(3))) unsigned int*)lds,
        16, 0, 0);
}

// ---- prep: blocks [0,NGATE) gate+x->bf16 + DIRECT scatter (compact fused via
// global atomics; per-expert list order is arbitrary but each entry carries
// token*2+slot and gate, so downstream output is order-independent).
// Blocks [NGATE,..) convert expert_w to bf16. counts[] memset to 0 before launch.
__global__ __launch_bounds__(256)
void prep_kernel(const float* __restrict__ w, u16* __restrict__ wbf,
                 const float* __restrict__ x,
                 const float* __restrict__ gate_w,
                 const float* __restrict__ gate_b,
                 u16* __restrict__ xbf,
                 int* __restrict__ counts,        // [NE], pre-zeroed
                 int* __restrict__ tok_list,      // [NE][N_TOK] token*2+slot
                 float* __restrict__ gate_list)   // [NE][N_TOK]
{
    int bid = blockIdx.x;
    if (bid >= NGATE) {
        size_t i = (size_t)(bid - NGATE) * 256 + threadIdx.x;   // float4 index
        float4 v = ((const float4*)w)[i];
        ushort4 b;
        b.x = f2bf(v.x); b.y = f2bf(v.y); b.z = f2bf(v.z); b.w = f2bf(v.w);
        ((ushort4*)wbf)[i] = b;
        return;
    }
    int wave = threadIdx.x >> 6, lane = threadIdx.x & 63;
    int t = bid * 4 + wave;
    const float4* xt = (const float4*)(x + (size_t)t * HDIM);
    ushort4* xb = (ushort4*)(xbf + (size_t)t * HDIM);

    float acc[NE];
#pragma unroll
    for (int e = 0; e < NE; ++e) acc[e] = 0.f;

#pragma unroll
    for (int i = 0; i < 4; ++i) {
        int f = i * 64 + lane;
        float4 v = xt[f];
        ushort4 b;
        b.x = f2bf(v.x); b.y = f2bf(v.y); b.z = f2bf(v.z); b.w = f2bf(v.w);
        xb[f] = b;
#pragma unroll
        for (int e = 0; e < NE; ++e) {
            float4 wv = ((const float4*)(gate_w + e * HDIM))[f];
            acc[e] += v.x * wv.x + v.y * wv.y + v.z * wv.z + v.w * wv.w;
        }
    }
#pragma unroll
    for (int e = 0; e < NE; ++e)
        for (int off = 32; off > 0; off >>= 1)
            acc[e] += __shfl_down(acc[e], off);

    if (lane == 0) {
        float logit[NE];
        float mx = -1e30f;
#pragma unroll
        for (int e = 0; e < NE; ++e) {
            logit[e] = acc[e] + gate_b[e];
            mx = fmaxf(mx, logit[e]);
        }
        float p[NE], s = 0.f;
#pragma unroll
        for (int e = 0; e < NE; ++e) { p[e] = expf(logit[e] - mx); s += p[e]; }
        float inv = 1.f / s;
        int i0 = 0;
#pragma unroll
        for (int e = 1; e < NE; ++e) if (logit[e] > logit[i0]) i0 = e;
        int i1 = (i0 == 0) ? 1 : 0;
#pragma unroll
        for (int e = 0; e < NE; ++e) if (e != i0 && logit[e] > logit[i1]) i1 = e;

        // fused compact: rank via device-scope atomic, scatter directly
        int p0 = atomicAdd(&counts[i0], 1);
        tok_list[i0 * N_TOK + p0]  = t * 2;          // token*2 + slot0
        gate_list[i0 * N_TOK + p0] = p[i0] * inv;
        int p1 = atomicAdd(&counts[i1], 1);
        tok_list[i1 * N_TOK + p1]  = t * 2 + 1;      // token*2 + slot1
        gate_list[i1 * N_TOK + p1] = p[i1] * inv;
    }
}

// ---- grouped per-expert GEMM, 128x128 tile, 4 waves, BK=32, counted-vmcnt dbuf ----
// Mapping: bid = (m*8 + n)*8 + e  =>  XCD (bid%8) == expert e (keeps round-1's
// FETCH 81->29MB L2-pinning win). LDS = 2buf x (8KB A + 8KB B) = 32 KB ->
// 5 blocks/CU (20 waves): co-resident independent blocks hide each other's
// barrier stalls (m114), which the 64KB/2-block round-3 version lacked.
// Swizzle (4 chunks/row now): row stride 32bf16=64B=16 banks, so row parity
// picks bank-half; XOR key must vary across even rows -> key=(row>>1)&3.
// Store side: physical chunk p at slot s holds logical chunk p^key(row) via
// pre-swizzled global source (rule-21 both-sides); read side applies same XOR.
// Balanced: every (half,quad-slot) serves exactly 2 lanes -> free (m136).
// K-loop (counted vmcnt, NO drain in main loop):
//   prologue: stage(buf0,k0); stage(buf1,k1)   -> 8 loads/thread in flight
//   per kt:   vmcnt(4) [vmcnt(0) on last] ; s_barrier
//             8 ds_read_b128 + 16 MFMA per wave on buf[kt&1]
//             lgkmcnt(0); s_barrier; stage(buf, kt+2)
__global__ __launch_bounds__(256, 5)
void moe_gemm_kernel(const u16* __restrict__ xbf,
                     const u16* __restrict__ wbf,
                     const float* __restrict__ expert_b,
                     const int* __restrict__ counts,
                     const int* __restrict__ tok_list,
                     const float* __restrict__ gate_list,
                     float* __restrict__ out,      // slot0 partials
                     float* __restrict__ part1)    // slot1 partials
{
    int bid = blockIdx.x;
    int e   = bid & 7;                 // XCD pin
    int n0  = ((bid >> 3) & 7) * TILE;
    int m0  = (bid >> 6) * TILE;
    int cnt = counts[e];
    if (m0 >= cnt) return;

    __shared__ __align__(16) u16 As[2][512 * 8];   // 2 x 8 KB
    __shared__ __align__(16) u16 Bs[2][512 * 8];   // 2 x 8 KB  (32 KB total)

    int tid = threadIdx.x;
    int w = tid >> 6, l = tid & 63;

    const u16* aP[2];
    const u16* bP[2];
#pragma unroll
    for (int j = 0; j < 2; ++j) {
        int s = j * 256 + tid;          // slot 0..511
        int r = s >> 2;                 // row 0..127
        int cs = (s & 3) ^ ((r >> 1) & 3);   // pre-swizzled source chunk
        int tr = m0 + r; if (tr > cnt - 1) tr = cnt - 1;   // dup rows discarded in epilogue
        int lst = tok_list[e * N_TOK + tr];
        aP[j] = xbf + (size_t)(lst >> 1) * HDIM + cs * 8;
        bP[j] = wbf + (size_t)(e * HDIM + n0 + r) * HDIM + cs * 8;
    }

    int wm = (w >> 1) * 64, wn = (w & 1) * 64;   // 2M x 2N wave grid
    int lrow = l & 15, quad = l >> 4;

    f32x4 acc[4][4];
#pragma unroll
    for (int mi = 0; mi < 4; ++mi)
#pragma unroll
        for (int ni = 0; ni < 4; ++ni)
            acc[mi][ni] = (f32x4){0.f, 0.f, 0.f, 0.f};

    auto stage = [&](int b, int k0) {
#pragma unroll
        for (int j = 0; j < 2; ++j) {
            gld_lds16(aP[j] + k0, &As[b][(size_t)(j * 256 + w * 64) * 8]);
            gld_lds16(bP[j] + k0, &Bs[b][(size_t)(j * 256 + w * 64) * 8]);
        }
    };

    // prologue: both buffers in flight (4 loads/thread each)
    stage(0, 0);
    stage(1, BK);

    int buf = 0;
    for (int kt = 0; kt < NKT; ++kt) {
        // this kt's batch (oldest 4 loads) retired; newer 4 stay in flight
        if (kt == NKT - 1) asm volatile("s_waitcnt vmcnt(0)" ::: "memory");
        else               asm volatile("s_waitcnt vmcnt(4)" ::: "memory");
        __builtin_amdgcn_s_barrier();

        const u16* Ab = As[buf];
        const u16* Bb = Bs[buf];
        bf16x8 af[4], bfr[4];
#pragma unroll
        for (int i = 0; i < 4; ++i) {
            int ra = wm + i * 16 + lrow;
            int rb = wn + i * 16 + lrow;
            af[i]  = *(const bf16x8*)(Ab + (size_t)(ra * 4 + (quad ^ ((ra >> 1) & 3))) * 8);
            bfr[i] = *(const bf16x8*)(Bb + (size_t)(rb * 4 + (quad ^ ((rb >> 1) & 3))) * 8);
        }
#pragma unroll
        for (int mi = 0; mi < 4; ++mi)
#pragma unroll
            for (int ni = 0; ni < 4; ++ni)
                acc[mi][ni] = __builtin_amdgcn_mfma_f32_16x16x32_bf16(
                    af[mi], bfr[ni], acc[mi][ni], 0, 0, 0);

        asm volatile("s_waitcnt lgkmcnt(0)" ::: "memory");  // my ds_reads done
        __builtin_amdgcn_s_barrier();                       // everyone's reads done
        if (kt + 2 < NKT) stage(buf, (kt + 2) * BK);        // refill freed buffer
        buf ^= 1;
    }

    // epilogue: bias + gate, plain stores to (token,slot) partial rows
#pragma unroll
    for (int mi = 0; mi < 4; ++mi) {
#pragma unroll
        for (int rr = 0; rr < 4; ++rr) {
            int listRow = m0 + wm + mi * 16 + quad * 4 + rr;
            if (listRow < cnt) {
                int   lst = tok_list[e * N_TOK + listRow];
                float g   = gate_list[e * N_TOK + listRow];
                float* dst = ((lst & 1) ? part1 : out) + (size_t)(lst >> 1) * HDIM;
#pragma unroll
                for (int ni = 0; ni < 4; ++ni) {
                    int col = n0 + wn + ni * 16 + lrow;
                    dst[col] = (acc[mi][ni][rr] + expert_b[e * HDIM + col]) * g;
                }
            }
        }
    }
}

// ---- combine: out += part1 ----
__global__ __launch_bounds__(256)
void combine_kernel(float* __restrict__ out, const float* __restrict__ part1) {
    size_t i = (size_t)blockIdx.x * 256 + threadIdx.x;
    float4 a = ((const float4*)out)[i];
    float4 b = ((const float4*)part1)[i];
    a.x += b.x; a.y += b.y; a.z += b.z; a.w += b.w;
    ((float4*)out)[i] = a;
}

extern "C" void kernel_launch(void* const* d_in, const int* in_sizes, int n_in,
                              void* d_out, int out_size, void* d_ws, size_t ws_size,
                              hipStream_t stream)
{
    const float* x        = (const float*)d_in[0];
    const float* gate_w   = (const float*)d_in[1];
    const float* gate_b   = (const float*)d_in[2];
    const float* expert_w = (const float*)d_in[3];
    const float* expert_b = (const float*)d_in[4];
    float* out = (float*)d_out;

    char* ws = (char*)d_ws;
    int*    counts    = (int*)(ws + (132 << 10));           // 32 B
    int*    tok_list  = (int*)(ws + (136 << 10));           // 256 KB
    float*  gate_list = (float*)(ws + (136 << 10) + NE * N_TOK * 4); // 256 KB
    u16*    xbf       = (u16*)(ws + (1 << 20));             // 16 MB
    u16*    wbf       = xbf + (size_t)N_TOK * HDIM;         // 16 MB
    float*  part1     = (float*)(ws + (33u << 20));         // 32 MB

    hipMemsetAsync(counts, 0, NE * sizeof(int), stream);

    prep_kernel<<<NCONV + NGATE, 256, 0, stream>>>(expert_w, wbf, x, gate_w, gate_b,
                                                   xbf, counts, tok_list, gate_list);

    moe_gemm_kernel<<<GEMM_GRID, 256, 0, stream>>>(xbf, wbf, expert_b,
                                                   counts, tok_list, gate_list, out, part1);

    combine_kernel<<<N_TOK * HDIM / 4 / 256, 256, 0, stream>>>(out, part1);
}

// Round 5
// 208.048 us; speedup vs baseline: 1.9918x; 1.9918x over previous
//
#include <hip/hip_runtime.h>
#include <hip/hip_bf16.h>
#include <math.h>

#define N_TOK 8192
#define HDIM  1024
#define NE    8
#define TILE  128
#define BK    64
#define NKT   (HDIM / BK)          // 16 K-steps
#define MT_MAX 64                  // 64*128 = 8192 rows capacity per expert (fully general)
#define NT_N  (HDIM / TILE)        // 8 n-tiles
#define GEMM_GRID (NE * NT_N * MT_MAX)   // 4096 blocks, ~1090 active when balanced
#define NGATE (N_TOK / 16)         // 512 gate blocks (16 tokens each, 4/wave)
#define NCONV 2048                 // convert_w blocks (4 float4 / thread)

typedef __attribute__((ext_vector_type(8))) short bf16x8;
typedef __attribute__((ext_vector_type(4))) float f32x4;
typedef unsigned short u16;

__device__ __forceinline__ u16 f2bf(float f) {
    union { float f; unsigned u; } v; v.f = f;
    unsigned r = v.u + 0x7FFFu + ((v.u >> 16) & 1u);   // round-to-nearest-even
    return (u16)(r >> 16);
}

__device__ __forceinline__ void gld_lds16(const void* g, void* lds) {
    __builtin_amdgcn_global_load_lds(
        (const __attribute__((address_space(1))) unsigned int*)g,
        (__attribute__((address_space(3))) unsigned int*)lds,
        16, 0, 0);
}

// ---- prep ----
// Blocks [0,NGATE): gate + x->bf16. Each wave handles 4 tokens: gate_w float4
// loaded ONCE per (i,e) and reused across the 4 tokens (round-3 re-read it per
// token: 144 VMEM/wave -> 48) and 4 independent acc chains give 4x MLP for
// latency hiding (round-4 showed prep is latency-bound: VALU 4.5%, HBM 2%).
// Blocks [NGATE,..): expert_w -> bf16, 4 float4/thread grid-stride.
__global__ __launch_bounds__(256)
void prep_kernel(const float* __restrict__ w, u16* __restrict__ wbf,
                 const float* __restrict__ x,
                 const float* __restrict__ gate_w,
                 const float* __restrict__ gate_b,
                 u16* __restrict__ xbf,
                 int* __restrict__ eids,       // [N_TOK] e0 | e1<<8
                 float2* __restrict__ gatesv)  // [N_TOK] (g0,g1)
{
    int bid = blockIdx.x;
    if (bid >= NGATE) {
        size_t base = (size_t)(bid - NGATE) * 1024 + threadIdx.x;   // float4 index
#pragma unroll
        for (int it = 0; it < 4; ++it) {
            size_t i = base + (size_t)it * 256;
            float4 v = ((const float4*)w)[i];
            ushort4 b;
            b.x = f2bf(v.x); b.y = f2bf(v.y); b.z = f2bf(v.z); b.w = f2bf(v.w);
            ((ushort4*)wbf)[i] = b;
        }
        return;
    }
    int wave = threadIdx.x >> 6, lane = threadIdx.x & 63;
    int tbase = bid * 16 + wave * 4;                 // 4 tokens per wave

    const float4* xt[4];
    ushort4* xb[4];
#pragma unroll
    for (int j = 0; j < 4; ++j) {
        xt[j] = (const float4*)(x + (size_t)(tbase + j) * HDIM);
        xb[j] = (ushort4*)(xbf + (size_t)(tbase + j) * HDIM);
    }

    float acc[4][NE];
#pragma unroll
    for (int j = 0; j < 4; ++j)
#pragma unroll
        for (int e = 0; e < NE; ++e) acc[j][e] = 0.f;

#pragma unroll
    for (int i = 0; i < 4; ++i) {
        int f = i * 64 + lane;
        float4 gw[NE];
#pragma unroll
        for (int e = 0; e < NE; ++e)
            gw[e] = ((const float4*)(gate_w + e * HDIM))[f];
#pragma unroll
        for (int j = 0; j < 4; ++j) {
            float4 v = xt[j][f];
            ushort4 b;
            b.x = f2bf(v.x); b.y = f2bf(v.y); b.z = f2bf(v.z); b.w = f2bf(v.w);
            xb[j][f] = b;
#pragma unroll
            for (int e = 0; e < NE; ++e)
                acc[j][e] += v.x * gw[e].x + v.y * gw[e].y + v.z * gw[e].z + v.w * gw[e].w;
        }
    }
#pragma unroll
    for (int j = 0; j < 4; ++j)
#pragma unroll
        for (int e = 0; e < NE; ++e)
            for (int off = 32; off > 0; off >>= 1)
                acc[j][e] += __shfl_down(acc[j][e], off);

    if (lane == 0) {
#pragma unroll
        for (int j = 0; j < 4; ++j) {
            int t = tbase + j;
            float logit[NE];
            float mx = -1e30f;
#pragma unroll
            for (int e = 0; e < NE; ++e) {
                logit[e] = acc[j][e] + gate_b[e];
                mx = fmaxf(mx, logit[e]);
            }
            float p[NE], s = 0.f;
#pragma unroll
            for (int e = 0; e < NE; ++e) { p[e] = expf(logit[e] - mx); s += p[e]; }
            float inv = 1.f / s;
            int i0 = 0;
#pragma unroll
            for (int e = 1; e < NE; ++e) if (logit[e] > logit[i0]) i0 = e;
            int i1 = (i0 == 0) ? 1 : 0;
#pragma unroll
            for (int e = 0; e < NE; ++e) if (e != i0 && logit[e] > logit[i1]) i1 = e;

            eids[t]   = i0 | (i1 << 8);
            gatesv[t] = make_float2(p[i0] * inv, p[i1] * inv);
        }
    }
}

// ---- compact: single block, hist+rank+scatter (16 sub-histograms) ----
// (round-3 verbatim: sorted-by-token lists, no global atomic contention)
__global__ __launch_bounds__(1024)
void compact_kernel(const int* __restrict__ eids,
                    const float2* __restrict__ gatesv,
                    int* __restrict__ tok_list, float* __restrict__ gate_list,
                    int* __restrict__ counts)
{
    __shared__ int lh[16][NE];
    __shared__ int lbase[16][NE];
    int tid = threadIdx.x;
    if (tid < 16 * NE) ((int*)lh)[tid] = 0;
    __syncthreads();
    int bucket = tid & 15;

    int e0v[8], e1v[8], r0v[8], r1v[8];
    float2 gv[8];
#pragma unroll
    for (int it = 0; it < 8; ++it) {
        int t = it * 1024 + tid;
        int ee = eids[t];
        e0v[it] = ee & 255; e1v[it] = (ee >> 8) & 255;
        gv[it] = gatesv[t];
        r0v[it] = atomicAdd(&lh[bucket][e0v[it]], 1);
        r1v[it] = atomicAdd(&lh[bucket][e1v[it]], 1);
    }
    __syncthreads();
    if (tid < NE) {
        int run = 0;
        for (int b = 0; b < 16; ++b) { lbase[b][tid] = run; run += lh[b][tid]; }
        counts[tid] = run;
    }
    __syncthreads();
#pragma unroll
    for (int it = 0; it < 8; ++it) {
        int t = it * 1024 + tid;
        int p0 = lbase[bucket][e0v[it]] + r0v[it];
        tok_list[e0v[it] * N_TOK + p0]  = t * 2;        // token*2 + slot
        gate_list[e0v[it] * N_TOK + p0] = gv[it].x;
        int p1 = lbase[bucket][e1v[it]] + r1v[it];
        tok_list[e1v[it] * N_TOK + p1]  = t * 2 + 1;
        gate_list[e1v[it] * N_TOK + p1] = gv[it].y;
    }
}

// ---- grouped per-expert GEMM (round-3 verbatim: 64.2us, MfmaUtil 21.7%, 0 conflicts)
// 128x128 tile, 4 waves, BK=64, counted-vmcnt double-buffer, expert->XCD pinning.
__global__ __launch_bounds__(256, 2)
void moe_gemm_kernel(const u16* __restrict__ xbf,
                     const u16* __restrict__ wbf,
                     const float* __restrict__ expert_b,
                     const int* __restrict__ counts,
                     const int* __restrict__ tok_list,
                     const float* __restrict__ gate_list,
                     float* __restrict__ out,      // slot0 partials
                     float* __restrict__ part1)    // slot1 partials
{
    int bid = blockIdx.x;
    int e   = bid & 7;                 // XCD pin
    int n0  = ((bid >> 3) & 7) * TILE;
    int m0  = (bid >> 6) * TILE;
    int cnt = counts[e];
    if (m0 >= cnt) return;

    __shared__ __align__(16) u16 As[2][1024 * 8];   // 2 x 16 KB
    __shared__ __align__(16) u16 Bs[2][1024 * 8];   // 2 x 16 KB  (64 KB total)

    int tid = threadIdx.x;
    int w = tid >> 6, l = tid & 63;

    const u16* aP[4];
    const u16* bP[4];
#pragma unroll
    for (int j = 0; j < 4; ++j) {
        int s = j * 256 + tid;          // slot 0..1023
        int r = s >> 3;                 // row 0..127
        int cs = (s & 7) ^ (r & 7);     // pre-swizzled source chunk
        int tr = m0 + r; if (tr > cnt - 1) tr = cnt - 1;   // dup rows discarded in epilogue
        int lst = tok_list[e * N_TOK + tr];
        aP[j] = xbf + (size_t)(lst >> 1) * HDIM + cs * 8;
        bP[j] = wbf + (size_t)(e * HDIM + n0 + r) * HDIM + cs * 8;
    }

    int wm = (w >> 1) * 64, wn = (w & 1) * 64;   // 2M x 2N wave grid
    int lrow = l & 15, quad = l >> 4;
    int cxbase = lrow & 7;

    f32x4 acc[4][4];
#pragma unroll
    for (int mi = 0; mi < 4; ++mi)
#pragma unroll
        for (int ni = 0; ni < 4; ++ni)
            acc[mi][ni] = (f32x4){0.f, 0.f, 0.f, 0.f};

    auto stage = [&](int b, int k0) {
#pragma unroll
        for (int j = 0; j < 4; ++j) {
            gld_lds16(aP[j] + k0, &As[b][(size_t)(j * 256 + w * 64) * 8]);
            gld_lds16(bP[j] + k0, &Bs[b][(size_t)(j * 256 + w * 64) * 8]);
        }
    };

    // prologue: both buffers in flight (8 loads/thread each)
    stage(0, 0);
    stage(1, BK);

    int buf = 0;
    for (int kt = 0; kt < NKT; ++kt) {
        // this kt's batch (oldest 8 loads) retired; newer 8 stay in flight
        if (kt == NKT - 1) asm volatile("s_waitcnt vmcnt(0)" ::: "memory");
        else               asm volatile("s_waitcnt vmcnt(8)" ::: "memory");
        __builtin_amdgcn_s_barrier();

        const u16* Ab = As[buf];
        const u16* Bb = Bs[buf];
#pragma unroll
        for (int kk = 0; kk < 2; ++kk) {
            int cx = (kk * 4 + quad) ^ cxbase;              // swizzled chunk for this lane
            bf16x8 af[4], bfr[4];
#pragma unroll
            for (int i = 0; i < 4; ++i) {
                int ra = wm + i * 16 + lrow;
                int rb = wn + i * 16 + lrow;
                af[i]  = *(const bf16x8*)(Ab + (size_t)(ra * 8 + cx) * 8);
                bfr[i] = *(const bf16x8*)(Bb + (size_t)(rb * 8 + cx) * 8);
            }
#pragma unroll
            for (int mi = 0; mi < 4; ++mi)
#pragma unroll
                for (int ni = 0; ni < 4; ++ni)
                    acc[mi][ni] = __builtin_amdgcn_mfma_f32_16x16x32_bf16(
                        af[mi], bfr[ni], acc[mi][ni], 0, 0, 0);
        }

        asm volatile("s_waitcnt lgkmcnt(0)" ::: "memory");  // my ds_reads done
        __builtin_amdgcn_s_barrier();                       // everyone's reads done
        if (kt + 2 < NKT) stage(buf, (kt + 2) * BK);        // refill freed buffer
        buf ^= 1;
    }

    // epilogue: bias + gate, plain stores to (token,slot) partial rows
#pragma unroll
    for (int mi = 0; mi < 4; ++mi) {
#pragma unroll
        for (int rr = 0; rr < 4; ++rr) {
            int listRow = m0 + wm + mi * 16 + quad * 4 + rr;
            if (listRow < cnt) {
                int   lst = tok_list[e * N_TOK + listRow];
                float g   = gate_list[e * N_TOK + listRow];
                float* dst = ((lst & 1) ? part1 : out) + (size_t)(lst >> 1) * HDIM;
#pragma unroll
                for (int ni = 0; ni < 4; ++ni) {
                    int col = n0 + wn + ni * 16 + lrow;
                    dst[col] = (acc[mi][ni][rr] + expert_b[e * HDIM + col]) * g;
                }
            }
        }
    }
}

// ---- combine: out += part1 ----
__global__ __launch_bounds__(256)
void combine_kernel(float* __restrict__ out, const float* __restrict__ part1) {
    size_t i = (size_t)blockIdx.x * 256 + threadIdx.x;
    float4 a = ((const float4*)out)[i];
    float4 b = ((const float4*)part1)[i];
    a.x += b.x; a.y += b.y; a.z += b.z; a.w += b.w;
    ((float4*)out)[i] = a;
}

extern "C" void kernel_launch(void* const* d_in, const int* in_sizes, int n_in,
                              void* d_out, int out_size, void* d_ws, size_t ws_size,
                              hipStream_t stream)
{
    const float* x        = (const float*)d_in[0];
    const float* gate_w   = (const float*)d_in[1];
    const float* gate_b   = (const float*)d_in[2];
    const float* expert_w = (const float*)d_in[3];
    const float* expert_b = (const float*)d_in[4];
    float* out = (float*)d_out;

    char* ws = (char*)d_ws;
    int*    eids      = (int*)(ws);                         // 32 KB
    float2* gatesv    = (float2*)(ws + (64 << 10));         // 64 KB
    int*    counts    = (int*)(ws + (132 << 10));           // 256 B
    int*    tok_list  = (int*)(ws + (136 << 10));           // 256 KB
    float*  gate_list = (float*)(ws + (136 << 10) + NE * N_TOK * 4); // 256 KB
    u16*    xbf       = (u16*)(ws + (1 << 20));             // 16 MB
    u16*    wbf       = xbf + (size_t)N_TOK * HDIM;         // 16 MB
    float*  part1     = (float*)(ws + (33u << 20));         // 32 MB

    prep_kernel<<<NCONV + NGATE, 256, 0, stream>>>(expert_w, wbf, x, gate_w, gate_b,
                                                   xbf, eids, gatesv);
    compact_kernel<<<1, 1024, 0, stream>>>(eids, gatesv, tok_list, gate_list, counts);

    moe_gemm_kernel<<<GEMM_GRID, 256, 0, stream>>>(xbf, wbf, expert_b,
                                                   counts, tok_list, gate_list, out, part1);

    combine_kernel<<<N_TOK * HDIM / 4 / 256, 256, 0, stream>>>(out, part1);
}

// Round 6
// 199.969 us; speedup vs baseline: 2.0723x; 1.0404x over previous
//
#include <hip/hip_runtime.h>
#include <hip/hip_bf16.h>
#include <math.h>

#define N_TOK 8192
#define HDIM  1024
#define NE    8
#define TILE  128
#define BK    64
#define NKT   (HDIM / BK)          // 16 K-steps
#define MT_MAX 64                  // 64*128 = 8192 rows capacity per expert (fully general)
#define NT_N  (HDIM / TILE)        // 8 n-tiles
#define GEMM_GRID (NE * NT_N * MT_MAX)   // 4096 blocks, ~1090 active when balanced
#define NGATE (N_TOK / 16)         // 512 gate blocks (16 tokens each, 4/wave)
#define NCONV 2048                 // convert_w blocks (4 float4 / thread)

typedef __attribute__((ext_vector_type(8))) short bf16x8;
typedef __attribute__((ext_vector_type(4))) float f32x4;
typedef unsigned short u16;

__device__ __forceinline__ u16 f2bf(float f) {
    union { float f; unsigned u; } v; v.f = f;
    unsigned r = v.u + 0x7FFFu + ((v.u >> 16) & 1u);   // round-to-nearest-even
    return (u16)(r >> 16);
}

__device__ __forceinline__ void gld_lds16(const void* g, void* lds) {
    __builtin_amdgcn_global_load_lds(
        (const __attribute__((address_space(1))) unsigned int*)g,
        (__attribute__((address_space(3))) unsigned int*)lds,
        16, 0, 0);
}

// ---- prep ----
// Blocks [0,NGATE): gate + x->bf16, 4 tokens/wave. All 16 x float4 loads hoisted
// ahead of the gate_w loop (16 independent VMEM in flight; round-5's VGPR-56
// version serialized them 4 at a time). gate_w loaded once per (i,e), reused
// across the 4 tokens. Blocks [NGATE,..): expert_w -> bf16, 4 float4/thread.
__global__ __launch_bounds__(256)
void prep_kernel(const float* __restrict__ w, u16* __restrict__ wbf,
                 const float* __restrict__ x,
                 const float* __restrict__ gate_w,
                 const float* __restrict__ gate_b,
                 u16* __restrict__ xbf,
                 int* __restrict__ eids,       // [N_TOK] e0 | e1<<8
                 float2* __restrict__ gatesv)  // [N_TOK] (g0,g1)
{
    int bid = blockIdx.x;
    if (bid >= NGATE) {
        size_t base = (size_t)(bid - NGATE) * 1024 + threadIdx.x;   // float4 index
#pragma unroll
        for (int it = 0; it < 4; ++it) {
            size_t i = base + (size_t)it * 256;
            float4 v = ((const float4*)w)[i];
            ushort4 b;
            b.x = f2bf(v.x); b.y = f2bf(v.y); b.z = f2bf(v.z); b.w = f2bf(v.w);
            ((ushort4*)wbf)[i] = b;
        }
        return;
    }
    int wave = threadIdx.x >> 6, lane = threadIdx.x & 63;
    int tbase = bid * 16 + wave * 4;                 // 4 tokens per wave

    const float4* xt[4];
    ushort4* xb[4];
#pragma unroll
    for (int j = 0; j < 4; ++j) {
        xt[j] = (const float4*)(x + (size_t)(tbase + j) * HDIM);
        xb[j] = (ushort4*)(xbf + (size_t)(tbase + j) * HDIM);
    }

    // hoist all 16 x loads (4 tokens x 4 fragments) -> max MLP
    float4 xv[4][4];   // [i][j]
#pragma unroll
    for (int i = 0; i < 4; ++i)
#pragma unroll
        for (int j = 0; j < 4; ++j)
            xv[i][j] = xt[j][i * 64 + lane];

    // bf16 conversion + store
#pragma unroll
    for (int i = 0; i < 4; ++i)
#pragma unroll
        for (int j = 0; j < 4; ++j) {
            float4 v = xv[i][j];
            ushort4 b;
            b.x = f2bf(v.x); b.y = f2bf(v.y); b.z = f2bf(v.z); b.w = f2bf(v.w);
            xb[j][i * 64 + lane] = b;
        }

    float acc[4][NE];
#pragma unroll
    for (int j = 0; j < 4; ++j)
#pragma unroll
        for (int e = 0; e < NE; ++e) acc[j][e] = 0.f;

#pragma unroll
    for (int i = 0; i < 4; ++i) {
        int f = i * 64 + lane;
        float4 gw[NE];
#pragma unroll
        for (int e = 0; e < NE; ++e)
            gw[e] = ((const float4*)(gate_w + e * HDIM))[f];
#pragma unroll
        for (int j = 0; j < 4; ++j) {
            float4 v = xv[i][j];
#pragma unroll
            for (int e = 0; e < NE; ++e)
                acc[j][e] += v.x * gw[e].x + v.y * gw[e].y + v.z * gw[e].z + v.w * gw[e].w;
        }
    }
#pragma unroll
    for (int j = 0; j < 4; ++j)
#pragma unroll
        for (int e = 0; e < NE; ++e)
            for (int off = 32; off > 0; off >>= 1)
                acc[j][e] += __shfl_down(acc[j][e], off);

    if (lane == 0) {
#pragma unroll
        for (int j = 0; j < 4; ++j) {
            int t = tbase + j;
            float logit[NE];
            float mx = -1e30f;
#pragma unroll
            for (int e = 0; e < NE; ++e) {
                logit[e] = acc[j][e] + gate_b[e];
                mx = fmaxf(mx, logit[e]);
            }
            float p[NE], s = 0.f;
#pragma unroll
            for (int e = 0; e < NE; ++e) { p[e] = expf(logit[e] - mx); s += p[e]; }
            float inv = 1.f / s;
            int i0 = 0;
#pragma unroll
            for (int e = 1; e < NE; ++e) if (logit[e] > logit[i0]) i0 = e;
            int i1 = (i0 == 0) ? 1 : 0;
#pragma unroll
            for (int e = 0; e < NE; ++e) if (e != i0 && logit[e] > logit[i1]) i1 = e;

            eids[t]   = i0 | (i1 << 8);
            gatesv[t] = make_float2(p[i0] * inv, p[i1] * inv);
        }
    }
}

// ---- compact: 32 blocks (parallel; was 1 block serializing the machine).
// Per block: LDS sub-histograms over its 256 tokens, then ONE global atomicAdd
// per (block,expert) reserves the block's range in counts[] (256 atomics total
// -- round-4's failure was 16384 same-line atomics; this is noise), then
// scatter. List order = block arrival order: order-independence proven in
// round 4 (passed, same absmax). counts[] pre-zeroed by host memset.
__global__ __launch_bounds__(256)
void compact_kernel(const int* __restrict__ eids,
                    const float2* __restrict__ gatesv,
                    int* __restrict__ tok_list, float* __restrict__ gate_list,
                    int* __restrict__ counts)
{
    __shared__ int lh[16][NE];
    __shared__ int lbase[16][NE];
    int tid = threadIdx.x;
    int t = blockIdx.x * 256 + tid;
    if (tid < 16 * NE) ((int*)lh)[tid] = 0;
    __syncthreads();
    int bucket = tid & 15;

    int ee = eids[t];
    int e0 = ee & 255, e1 = (ee >> 8) & 255;
    float2 gv = gatesv[t];
    int r0 = atomicAdd(&lh[bucket][e0], 1);
    int r1 = atomicAdd(&lh[bucket][e1], 1);
    __syncthreads();

    if (tid < NE) {
        int pre[16];
        int run = 0;
#pragma unroll
        for (int b = 0; b < 16; ++b) { pre[b] = run; run += lh[b][tid]; }
        int base = atomicAdd(&counts[tid], run);    // device-scope block reservation
#pragma unroll
        for (int b = 0; b < 16; ++b) lbase[b][tid] = base + pre[b];
    }
    __syncthreads();

    int p0 = lbase[bucket][e0] + r0;
    tok_list[e0 * N_TOK + p0]  = t * 2;        // token*2 + slot
    gate_list[e0 * N_TOK + p0] = gv.x;
    int p1 = lbase[bucket][e1] + r1;
    tok_list[e1 * N_TOK + p1]  = t * 2 + 1;
    gate_list[e1 * N_TOK + p1] = gv.y;
}

// ---- grouped per-expert GEMM: 128x128 tile, 4 waves, BK=64, ONE-barrier 2-phase ----
// (catalog minimum-2-phase template: STAGE(next) at top of iter, compute current,
//  lgkmcnt(0)+vmcnt(0)+single s_barrier at bottom. vmcnt(0) is cheap because the
//  stage had the whole compute phase to land. Round-3..5's 2-barrier counted
//  version measured 64us / MfmaUtil 21.6%; this removes 16 barriers/block.)
// Mapping: bid = (m*8+n)*8 + e => XCD(bid%8)==expert e (FETCH 81->37MB win kept).
// Chunk-XOR swizzle both-sides (rule 21), 0 conflicts measured rounds 0-5.
__global__ __launch_bounds__(256, 2)
void moe_gemm_kernel(const u16* __restrict__ xbf,
                     const u16* __restrict__ wbf,
                     const float* __restrict__ expert_b,
                     const int* __restrict__ counts,
                     const int* __restrict__ tok_list,
                     const float* __restrict__ gate_list,
                     float* __restrict__ out,      // slot0 partials
                     float* __restrict__ part1)    // slot1 partials
{
    int bid = blockIdx.x;
    int e   = bid & 7;                 // XCD pin
    int n0  = ((bid >> 3) & 7) * TILE;
    int m0  = (bid >> 6) * TILE;
    int cnt = counts[e];
    if (m0 >= cnt) return;

    __shared__ __align__(16) u16 As[2][1024 * 8];   // 2 x 16 KB
    __shared__ __align__(16) u16 Bs[2][1024 * 8];   // 2 x 16 KB  (64 KB total)

    int tid = threadIdx.x;
    int w = tid >> 6, l = tid & 63;

    const u16* aP[4];
    const u16* bP[4];
#pragma unroll
    for (int j = 0; j < 4; ++j) {
        int s = j * 256 + tid;          // slot 0..1023
        int r = s >> 3;                 // row 0..127
        int cs = (s & 7) ^ (r & 7);     // pre-swizzled source chunk
        int tr = m0 + r; if (tr > cnt - 1) tr = cnt - 1;   // dup rows discarded in epilogue
        int lst = tok_list[e * N_TOK + tr];
        aP[j] = xbf + (size_t)(lst >> 1) * HDIM + cs * 8;
        bP[j] = wbf + (size_t)(e * HDIM + n0 + r) * HDIM + cs * 8;
    }

    int wm = (w >> 1) * 64, wn = (w & 1) * 64;   // 2M x 2N wave grid
    int lrow = l & 15, quad = l >> 4;
    int cxbase = lrow & 7;

    f32x4 acc[4][4];
#pragma unroll
    for (int mi = 0; mi < 4; ++mi)
#pragma unroll
        for (int ni = 0; ni < 4; ++ni)
            acc[mi][ni] = (f32x4){0.f, 0.f, 0.f, 0.f};

    auto stage = [&](int b, int k0) {
#pragma unroll
        for (int j = 0; j < 4; ++j) {
            gld_lds16(aP[j] + k0, &As[b][(size_t)(j * 256 + w * 64) * 8]);
            gld_lds16(bP[j] + k0, &Bs[b][(size_t)(j * 256 + w * 64) * 8]);
        }
    };

    // prologue: buffer 0 staged and drained
    stage(0, 0);
    asm volatile("s_waitcnt vmcnt(0)" ::: "memory");
    __builtin_amdgcn_s_barrier();

    int buf = 0;
    for (int kt = 0; kt < NKT; ++kt) {
        if (kt + 1 < NKT) stage(buf ^ 1, (kt + 1) * BK);   // issue next-tile loads FIRST

        const u16* Ab = As[buf];
        const u16* Bb = Bs[buf];
#pragma unroll
        for (int kk = 0; kk < 2; ++kk) {
            int cx = (kk * 4 + quad) ^ cxbase;              // swizzled chunk for this lane
            bf16x8 af[4], bfr[4];
#pragma unroll
            for (int i = 0; i < 4; ++i) {
                int ra = wm + i * 16 + lrow;
                int rb = wn + i * 16 + lrow;
                af[i]  = *(const bf16x8*)(Ab + (size_t)(ra * 8 + cx) * 8);
                bfr[i] = *(const bf16x8*)(Bb + (size_t)(rb * 8 + cx) * 8);
            }
#pragma unroll
            for (int mi = 0; mi < 4; ++mi)
#pragma unroll
                for (int ni = 0; ni < 4; ++ni)
                    acc[mi][ni] = __builtin_amdgcn_mfma_f32_16x16x32_bf16(
                        af[mi], bfr[ni], acc[mi][ni], 0, 0, 0);
        }

        if (kt + 1 < NKT) {
            asm volatile("s_waitcnt lgkmcnt(0)" ::: "memory");  // my reads of buf done
            asm volatile("s_waitcnt vmcnt(0)" ::: "memory");    // next buf landed
            __builtin_amdgcn_s_barrier();                       // single barrier/K-step
        }
        buf ^= 1;
    }

    // epilogue: bias + gate, plain stores to (token,slot) partial rows
#pragma unroll
    for (int mi = 0; mi < 4; ++mi) {
#pragma unroll
        for (int rr = 0; rr < 4; ++rr) {
            int listRow = m0 + wm + mi * 16 + quad * 4 + rr;
            if (listRow < cnt) {
                int   lst = tok_list[e * N_TOK + listRow];
                float g   = gate_list[e * N_TOK + listRow];
                float* dst = ((lst & 1) ? part1 : out) + (size_t)(lst >> 1) * HDIM;
#pragma unroll
                for (int ni = 0; ni < 4; ++ni) {
                    int col = n0 + wn + ni * 16 + lrow;
                    dst[col] = (acc[mi][ni][rr] + expert_b[e * HDIM + col]) * g;
                }
            }
        }
    }
}

// ---- combine: out += part1 ----
__global__ __launch_bounds__(256)
void combine_kernel(float* __restrict__ out, const float* __restrict__ part1) {
    size_t i = (size_t)blockIdx.x * 256 + threadIdx.x;
    float4 a = ((const float4*)out)[i];
    float4 b = ((const float4*)part1)[i];
    a.x += b.x; a.y += b.y; a.z += b.z; a.w += b.w;
    ((float4*)out)[i] = a;
}

extern "C" void kernel_launch(void* const* d_in, const int* in_sizes, int n_in,
                              void* d_out, int out_size, void* d_ws, size_t ws_size,
                              hipStream_t stream)
{
    const float* x        = (const float*)d_in[0];
    const float* gate_w   = (const float*)d_in[1];
    const float* gate_b   = (const float*)d_in[2];
    const float* expert_w = (const float*)d_in[3];
    const float* expert_b = (const float*)d_in[4];
    float* out = (float*)d_out;

    char* ws = (char*)d_ws;
    int*    eids      = (int*)(ws);                         // 32 KB
    float2* gatesv    = (float2*)(ws + (64 << 10));         // 64 KB
    int*    counts    = (int*)(ws + (132 << 10));           // 32 B
    int*    tok_list  = (int*)(ws + (136 << 10));           // 256 KB
    float*  gate_list = (float*)(ws + (136 << 10) + NE * N_TOK * 4); // 256 KB
    u16*    xbf       = (u16*)(ws + (1 << 20));             // 16 MB
    u16*    wbf       = xbf + (size_t)N_TOK * HDIM;         // 16 MB
    float*  part1     = (float*)(ws + (33u << 20));         // 32 MB

    hipMemsetAsync(counts, 0, NE * sizeof(int), stream);

    prep_kernel<<<NCONV + NGATE, 256, 0, stream>>>(expert_w, wbf, x, gate_w, gate_b,
                                                   xbf, eids, gatesv);
    compact_kernel<<<N_TOK / 256, 256, 0, stream>>>(eids, gatesv, tok_list, gate_list, counts);

    moe_gemm_kernel<<<GEMM_GRID, 256, 0, stream>>>(xbf, wbf, expert_b,
                                                   counts, tok_list, gate_list, out, part1);

    combine_kernel<<<N_TOK * HDIM / 4 / 256, 256, 0, stream>>>(out, part1);
}

// Round 7
// 194.311 us; speedup vs baseline: 2.1326x; 1.0291x over previous
//
#include <hip/hip_runtime.h>
#include <hip/hip_bf16.h>
#include <math.h>

#define N_TOK 8192
#define HDIM  1024
#define NE    8
#define TILE  128
#define BK    64
#define NKT   (HDIM / BK)          // 16 K-steps
#define MT_MAX 64                  // 64*128 = 8192 rows capacity per expert (fully general)
#define NT_N  (HDIM / TILE)        // 8 n-tiles
#define GEMM_GRID (NE * NT_N * MT_MAX)   // 4096 blocks, ~1090 active when balanced
#define NGATE (N_TOK / 16)         // 512 gate blocks (16 tokens each, 4/wave)
#define NCONV 2048                 // convert_w blocks (4 float4 / thread)

typedef __attribute__((ext_vector_type(8))) short bf16x8;
typedef __attribute__((ext_vector_type(4))) float f32x4;
typedef unsigned short u16;

__device__ __forceinline__ u16 f2bf(float f) {
    union { float f; unsigned u; } v; v.f = f;
    unsigned r = v.u + 0x7FFFu + ((v.u >> 16) & 1u);   // round-to-nearest-even
    return (u16)(r >> 16);
}

__device__ __forceinline__ void gld_lds16(const void* g, void* lds) {
    __builtin_amdgcn_global_load_lds(
        (const __attribute__((address_space(1))) unsigned int*)g,
        (__attribute__((address_space(3))) unsigned int*)lds,
        16, 0, 0);
}

// ---- prep ----
// Blocks [0,NGATE): gate + x->bf16, 4 tokens/wave, all 16 x-loads hoisted (MLP).
// Blocks [NGATE,..): expert_w -> bf16, 4 float4/thread. Block NGATE also zeroes
// counts[] (replaces the hipMemsetAsync graph node; compact reads counts only
// after prep completes, enforced by stream order).
__global__ __launch_bounds__(256)
void prep_kernel(const float* __restrict__ w, u16* __restrict__ wbf,
                 const float* __restrict__ x,
                 const float* __restrict__ gate_w,
                 const float* __restrict__ gate_b,
                 u16* __restrict__ xbf,
                 int* __restrict__ eids,       // [N_TOK] e0 | e1<<8
                 float2* __restrict__ gatesv,  // [N_TOK] (g0,g1)
                 int* __restrict__ counts)     // [NE] zeroed here
{
    int bid = blockIdx.x;
    if (bid >= NGATE) {
        if (bid == NGATE && threadIdx.x < NE) counts[threadIdx.x] = 0;
        size_t base = (size_t)(bid - NGATE) * 1024 + threadIdx.x;   // float4 index
#pragma unroll
        for (int it = 0; it < 4; ++it) {
            size_t i = base + (size_t)it * 256;
            float4 v = ((const float4*)w)[i];
            ushort4 b;
            b.x = f2bf(v.x); b.y = f2bf(v.y); b.z = f2bf(v.z); b.w = f2bf(v.w);
            ((ushort4*)wbf)[i] = b;
        }
        return;
    }
    int wave = threadIdx.x >> 6, lane = threadIdx.x & 63;
    int tbase = bid * 16 + wave * 4;                 // 4 tokens per wave

    const float4* xt[4];
    ushort4* xb[4];
#pragma unroll
    for (int j = 0; j < 4; ++j) {
        xt[j] = (const float4*)(x + (size_t)(tbase + j) * HDIM);
        xb[j] = (ushort4*)(xbf + (size_t)(tbase + j) * HDIM);
    }

    // hoist all 16 x loads (4 tokens x 4 fragments) -> max MLP
    float4 xv[4][4];   // [i][j]
#pragma unroll
    for (int i = 0; i < 4; ++i)
#pragma unroll
        for (int j = 0; j < 4; ++j)
            xv[i][j] = xt[j][i * 64 + lane];

    // bf16 conversion + store
#pragma unroll
    for (int i = 0; i < 4; ++i)
#pragma unroll
        for (int j = 0; j < 4; ++j) {
            float4 v = xv[i][j];
            ushort4 b;
            b.x = f2bf(v.x); b.y = f2bf(v.y); b.z = f2bf(v.z); b.w = f2bf(v.w);
            xb[j][i * 64 + lane] = b;
        }

    float acc[4][NE];
#pragma unroll
    for (int j = 0; j < 4; ++j)
#pragma unroll
        for (int e = 0; e < NE; ++e) acc[j][e] = 0.f;

#pragma unroll
    for (int i = 0; i < 4; ++i) {
        int f = i * 64 + lane;
        float4 gw[NE];
#pragma unroll
        for (int e = 0; e < NE; ++e)
            gw[e] = ((const float4*)(gate_w + e * HDIM))[f];
#pragma unroll
        for (int j = 0; j < 4; ++j) {
            float4 v = xv[i][j];
#pragma unroll
            for (int e = 0; e < NE; ++e)
                acc[j][e] += v.x * gw[e].x + v.y * gw[e].y + v.z * gw[e].z + v.w * gw[e].w;
        }
    }
#pragma unroll
    for (int j = 0; j < 4; ++j)
#pragma unroll
        for (int e = 0; e < NE; ++e)
            for (int off = 32; off > 0; off >>= 1)
                acc[j][e] += __shfl_down(acc[j][e], off);

    if (lane == 0) {
#pragma unroll
        for (int j = 0; j < 4; ++j) {
            int t = tbase + j;
            float logit[NE];
            float mx = -1e30f;
#pragma unroll
            for (int e = 0; e < NE; ++e) {
                logit[e] = acc[j][e] + gate_b[e];
                mx = fmaxf(mx, logit[e]);
            }
            float p[NE], s = 0.f;
#pragma unroll
            for (int e = 0; e < NE; ++e) { p[e] = expf(logit[e] - mx); s += p[e]; }
            float inv = 1.f / s;
            int i0 = 0;
#pragma unroll
            for (int e = 1; e < NE; ++e) if (logit[e] > logit[i0]) i0 = e;
            int i1 = (i0 == 0) ? 1 : 0;
#pragma unroll
            for (int e = 0; e < NE; ++e) if (e != i0 && logit[e] > logit[i1]) i1 = e;

            eids[t]   = i0 | (i1 << 8);
            gatesv[t] = make_float2(p[i0] * inv, p[i1] * inv);
        }
    }
}

// ---- compact: 32 blocks, LDS sub-histograms + one block-range atomic per
// (block,expert) = 256 global atomics total (round-6 verified: -14us vs 1-block).
// List order = block arrival order (order-independent downstream).
__global__ __launch_bounds__(256)
void compact_kernel(const int* __restrict__ eids,
                    const float2* __restrict__ gatesv,
                    int* __restrict__ tok_list, float* __restrict__ gate_list,
                    int* __restrict__ counts)
{
    __shared__ int lh[16][NE];
    __shared__ int lbase[16][NE];
    int tid = threadIdx.x;
    int t = blockIdx.x * 256 + tid;
    if (tid < 16 * NE) ((int*)lh)[tid] = 0;
    __syncthreads();
    int bucket = tid & 15;

    int ee = eids[t];
    int e0 = ee & 255, e1 = (ee >> 8) & 255;
    float2 gv = gatesv[t];
    int r0 = atomicAdd(&lh[bucket][e0], 1);
    int r1 = atomicAdd(&lh[bucket][e1], 1);
    __syncthreads();

    if (tid < NE) {
        int pre[16];
        int run = 0;
#pragma unroll
        for (int b = 0; b < 16; ++b) { pre[b] = run; run += lh[b][tid]; }
        int base = atomicAdd(&counts[tid], run);    // device-scope block reservation
#pragma unroll
        for (int b = 0; b < 16; ++b) lbase[b][tid] = base + pre[b];
    }
    __syncthreads();

    int p0 = lbase[bucket][e0] + r0;
    tok_list[e0 * N_TOK + p0]  = t * 2;        // token*2 + slot
    gate_list[e0 * N_TOK + p0] = gv.x;
    int p1 = lbase[bucket][e1] + r1;
    tok_list[e1 * N_TOK + p1]  = t * 2 + 1;
    gate_list[e1 * N_TOK + p1] = gv.y;
}

// ---- grouped per-expert GEMM (round-3 VERBATIM: 64.2us, MfmaUtil 21.6%, 0 conflicts)
// 128x128 tile, 4 waves, BK=64, COUNTED-vmcnt double-buffer (vmcnt(8) in main loop,
// never 0 -- round-6's one-barrier/vmcnt(0) variant measured 70.5us, refuted).
// Mapping: bid = (m*8+n)*8 + e => XCD(bid%8)==expert e (FETCH 81->37MB win).
// Chunk-XOR swizzle both-sides (rule 21).
__global__ __launch_bounds__(256, 2)
void moe_gemm_kernel(const u16* __restrict__ xbf,
                     const u16* __restrict__ wbf,
                     const float* __restrict__ expert_b,
                     const int* __restrict__ counts,
                     const int* __restrict__ tok_list,
                     const float* __restrict__ gate_list,
                     float* __restrict__ out,      // slot0 partials
                     float* __restrict__ part1)    // slot1 partials
{
    int bid = blockIdx.x;
    int e   = bid & 7;                 // XCD pin
    int n0  = ((bid >> 3) & 7) * TILE;
    int m0  = (bid >> 6) * TILE;
    int cnt = counts[e];
    if (m0 >= cnt) return;

    __shared__ __align__(16) u16 As[2][1024 * 8];   // 2 x 16 KB
    __shared__ __align__(16) u16 Bs[2][1024 * 8];   // 2 x 16 KB  (64 KB total)

    int tid = threadIdx.x;
    int w = tid >> 6, l = tid & 63;

    const u16* aP[4];
    const u16* bP[4];
#pragma unroll
    for (int j = 0; j < 4; ++j) {
        int s = j * 256 + tid;          // slot 0..1023
        int r = s >> 3;                 // row 0..127
        int cs = (s & 7) ^ (r & 7);     // pre-swizzled source chunk
        int tr = m0 + r; if (tr > cnt - 1) tr = cnt - 1;   // dup rows discarded in epilogue
        int lst = tok_list[e * N_TOK + tr];
        aP[j] = xbf + (size_t)(lst >> 1) * HDIM + cs * 8;
        bP[j] = wbf + (size_t)(e * HDIM + n0 + r) * HDIM + cs * 8;
    }

    int wm = (w >> 1) * 64, wn = (w & 1) * 64;   // 2M x 2N wave grid
    int lrow = l & 15, quad = l >> 4;
    int cxbase = lrow & 7;

    f32x4 acc[4][4];
#pragma unroll
    for (int mi = 0; mi < 4; ++mi)
#pragma unroll
        for (int ni = 0; ni < 4; ++ni)
            acc[mi][ni] = (f32x4){0.f, 0.f, 0.f, 0.f};

    auto stage = [&](int b, int k0) {
#pragma unroll
        for (int j = 0; j < 4; ++j) {
            gld_lds16(aP[j] + k0, &As[b][(size_t)(j * 256 + w * 64) * 8]);
            gld_lds16(bP[j] + k0, &Bs[b][(size_t)(j * 256 + w * 64) * 8]);
        }
    };

    // prologue: both buffers in flight (8 loads/thread each)
    stage(0, 0);
    stage(1, BK);

    int buf = 0;
    for (int kt = 0; kt < NKT; ++kt) {
        // this kt's batch (oldest 8 loads) retired; newer 8 stay in flight
        if (kt == NKT - 1) asm volatile("s_waitcnt vmcnt(0)" ::: "memory");
        else               asm volatile("s_waitcnt vmcnt(8)" ::: "memory");
        __builtin_amdgcn_s_barrier();

        const u16* Ab = As[buf];
        const u16* Bb = Bs[buf];
#pragma unroll
        for (int kk = 0; kk < 2; ++kk) {
            int cx = (kk * 4 + quad) ^ cxbase;              // swizzled chunk for this lane
            bf16x8 af[4], bfr[4];
#pragma unroll
            for (int i = 0; i < 4; ++i) {
                int ra = wm + i * 16 + lrow;
                int rb = wn + i * 16 + lrow;
                af[i]  = *(const bf16x8*)(Ab + (size_t)(ra * 8 + cx) * 8);
                bfr[i] = *(const bf16x8*)(Bb + (size_t)(rb * 8 + cx) * 8);
            }
#pragma unroll
            for (int mi = 0; mi < 4; ++mi)
#pragma unroll
                for (int ni = 0; ni < 4; ++ni)
                    acc[mi][ni] = __builtin_amdgcn_mfma_f32_16x16x32_bf16(
                        af[mi], bfr[ni], acc[mi][ni], 0, 0, 0);
        }

        asm volatile("s_waitcnt lgkmcnt(0)" ::: "memory");  // my ds_reads done
        __builtin_amdgcn_s_barrier();                       // everyone's reads done
        if (kt + 2 < NKT) stage(buf, (kt + 2) * BK);        // refill freed buffer
        buf ^= 1;
    }

    // epilogue: bias + gate, plain stores to (token,slot) partial rows
#pragma unroll
    for (int mi = 0; mi < 4; ++mi) {
#pragma unroll
        for (int rr = 0; rr < 4; ++rr) {
            int listRow = m0 + wm + mi * 16 + quad * 4 + rr;
            if (listRow < cnt) {
                int   lst = tok_list[e * N_TOK + listRow];
                float g   = gate_list[e * N_TOK + listRow];
                float* dst = ((lst & 1) ? part1 : out) + (size_t)(lst >> 1) * HDIM;
#pragma unroll
                for (int ni = 0; ni < 4; ++ni) {
                    int col = n0 + wn + ni * 16 + lrow;
                    dst[col] = (acc[mi][ni][rr] + expert_b[e * HDIM + col]) * g;
                }
            }
        }
    }
}

// ---- combine: out += part1, 4 float4/thread (ILP for streaming) ----
__global__ __launch_bounds__(256)
void combine_kernel(float* __restrict__ out, const float* __restrict__ part1) {
    size_t base = (size_t)blockIdx.x * 1024 + threadIdx.x;
    float4 a[4], b[4];
#pragma unroll
    for (int it = 0; it < 4; ++it) {
        size_t i = base + (size_t)it * 256;
        a[it] = ((const float4*)out)[i];
        b[it] = ((const float4*)part1)[i];
    }
#pragma unroll
    for (int it = 0; it < 4; ++it) {
        size_t i = base + (size_t)it * 256;
        a[it].x += b[it].x; a[it].y += b[it].y;
        a[it].z += b[it].z; a[it].w += b[it].w;
        ((float4*)out)[i] = a[it];
    }
}

extern "C" void kernel_launch(void* const* d_in, const int* in_sizes, int n_in,
                              void* d_out, int out_size, void* d_ws, size_t ws_size,
                              hipStream_t stream)
{
    const float* x        = (const float*)d_in[0];
    const float* gate_w   = (const float*)d_in[1];
    const float* gate_b   = (const float*)d_in[2];
    const float* expert_w = (const float*)d_in[3];
    const float* expert_b = (const float*)d_in[4];
    float* out = (float*)d_out;

    char* ws = (char*)d_ws;
    int*    eids      = (int*)(ws);                         // 32 KB
    float2* gatesv    = (float2*)(ws + (64 << 10));         // 64 KB
    int*    counts    = (int*)(ws + (132 << 10));           // 32 B
    int*    tok_list  = (int*)(ws + (136 << 10));           // 256 KB
    float*  gate_list = (float*)(ws + (136 << 10) + NE * N_TOK * 4); // 256 KB
    u16*    xbf       = (u16*)(ws + (1 << 20));             // 16 MB
    u16*    wbf       = xbf + (size_t)N_TOK * HDIM;         // 16 MB
    float*  part1     = (float*)(ws + (33u << 20));         // 32 MB

    prep_kernel<<<NCONV + NGATE, 256, 0, stream>>>(expert_w, wbf, x, gate_w, gate_b,
                                                   xbf, eids, gatesv, counts);
    compact_kernel<<<N_TOK / 256, 256, 0, stream>>>(eids, gatesv, tok_list, gate_list, counts);

    moe_gemm_kernel<<<GEMM_GRID, 256, 0, stream>>>(xbf, wbf, expert_b,
                                                   counts, tok_list, gate_list, out, part1);

    combine_kernel<<<N_TOK * HDIM / 16 / 256, 256, 0, stream>>>(out, part1);
}